// Round 9
// baseline (184.444 us; speedup 1.0000x reference)
//
#include <hip/hip_runtime.h>

#define BATCH 8192
#define LOSC  2048.0f
#define LOINV (1.0f / 2048.0f)

typedef _Float16 f16x4 __attribute__((ext_vector_type(4)));
typedef __fp16   fp16x2 __attribute__((ext_vector_type(2)));
typedef float    f32x4 __attribute__((ext_vector_type(4)));

union PK2 { fp16x2 h; unsigned u; };
union U4  { f16x4 v; unsigned u[2]; };

__device__ __forceinline__ unsigned pkrtz(float a, float b) {
    PK2 p; p.h = __builtin_amdgcn_cvt_pkrtz(a, b); return p.u;
}
__device__ __forceinline__ float lo0(unsigned hp, float v) {
    PK2 p; p.u = hp; return (v - (float)p.h[0]) * LOSC;
}
__device__ __forceinline__ float lo1(unsigned hp, float v) {
    PK2 p; p.u = hp; return (v - (float)p.h[1]) * LOSC;
}

// ---------------------------------------------------------------------------
// Kernel 1: exact NN (CD=1). Reference distance sqrt(fl(dx*dx)) == |dx| in
// correctly-rounded fp32 -> compare fabsf(dx); first-index argmin preserved
// (strict < over ascending j), self excluded. ~5 us standalone (256 thr).
// ---------------------------------------------------------------------------
__global__ __launch_bounds__(256) void nn_kernel(const float* __restrict__ c,
                                                 float* __restrict__ c0) {
    __shared__ float cs[BATCH];
    const int t = threadIdx.x;
    {
        const float4* cg = (const float4*)c;
        float4* cl = (float4*)cs;
        for (int j = t; j < BATCH / 4; j += 256) cl[j] = cg[j];
    }
    __syncthreads();
    const int part = t & 31;
    const int i    = blockIdx.x * 8 + (t >> 5);
    const float ci = cs[i];
    const int sj0 = ((i & 3) == 0) ? (i >> 2) : -1;
    const int sj1 = ((i & 3) == 1) ? (i >> 2) : -1;
    const int sj2 = ((i & 3) == 2) ? (i >> 2) : -1;
    const int sj3 = ((i & 3) == 3) ? (i >> 2) : -1;
    const float4* cs4 = (const float4*)cs;
    float bd0 = 3e38f, bd1 = 3e38f, bd2 = 3e38f, bd3 = 3e38f;
    int   bj0 = 0,     bj1 = 0,     bj2 = 0,     bj3 = 0;
    #pragma unroll 4
    for (int tt = 0; tt < 64; ++tt) {
        const int jj = part + (tt << 5);
        const float4 v = cs4[jj];
        float d0 = fabsf(ci - v.x);
        float d1 = fabsf(ci - v.y);
        float d2 = fabsf(ci - v.z);
        float d3 = fabsf(ci - v.w);
        if (jj == sj0) d0 = 3e38f;
        if (jj == sj1) d1 = 3e38f;
        if (jj == sj2) d2 = 3e38f;
        if (jj == sj3) d3 = 3e38f;
        if (d0 < bd0) { bd0 = d0; bj0 = jj; }
        if (d1 < bd1) { bd1 = d1; bj1 = jj; }
        if (d2 < bd2) { bd2 = d2; bj2 = jj; }
        if (d3 < bd3) { bd3 = d3; bj3 = jj; }
    }
    float best = bd0; int bestj = bj0 * 4 + 0;
    { const int j1 = bj1 * 4 + 1; if (bd1 < best || (bd1 == best && j1 < bestj)) { best = bd1; bestj = j1; } }
    { const int j2 = bj2 * 4 + 2; if (bd2 < best || (bd2 == best && j2 < bestj)) { best = bd2; bestj = j2; } }
    { const int j3 = bj3 * 4 + 3; if (bd3 < best || (bd3 == best && j3 < bestj)) { best = bd3; bestj = j3; } }
    #pragma unroll
    for (int off = 1; off < 32; off <<= 1) {
        const float od = __shfl_xor(best, off);
        const int   oj = __shfl_xor(bestj, off);
        if (od < best || (od == best && oj < bestj)) { best = od; bestj = oj; }
    }
    if (part == 0) c0[i] = cs[bestj];
}

// ---------------------------------------------------------------------------
// Kernel 2 (v9): 8 samples/wave, 1024 blocks x 1 wave. Split-f16 via
// mfma_f32_16x16x16_f16 (K=16): B k-map (q*4+j) == C/D row map (q*4+r) ->
// zero-shfl inter-layer transform. All weights (hi+lo) in registers; no LDS.
// Chain surgery for 1-wave/SIMD: m-outer/T-inner MFMA interleave (dep reuse
// distance 12), aL split into two accumulators, g-reduce as 4 parallel FMA
// chains + 3 PARALLEL shfl_xor(16,32,48) (one latency window; commutative
// adds keep y bitwise-uniform across the lane orbit).
// ---------------------------------------------------------------------------
__global__ __launch_bounds__(64, 1) void solve_kernel(
    const float* __restrict__ x, const float* __restrict__ c0g,
    const float* __restrict__ W1, const float* __restrict__ b1,
    const float* __restrict__ W2, const float* __restrict__ b2,
    const float* __restrict__ W3, const float* __restrict__ b3,
    const float* __restrict__ W4, float* __restrict__ out)
{
    const int lane = threadIdx.x & 63;
    const int q  = lane >> 4;
    const int cc = lane & 15;
    const bool fwd = (cc < 8);
    const int s = cc & 7;
    const int sbase = blockIdx.x * 8;

    // ---- W2/W3 hi+lo fragments, all registers ----
    // A-frag (T,m): lane holds W[(T*16+cc)][m*16 + q*4 + j], j=0..3
    f16x4 W2h[4][4], W2l[4][4], W3h[4][4], W3l[4][4];
    #pragma unroll
    for (int T = 0; T < 4; ++T)
        #pragma unroll
        for (int m = 0; m < 4; ++m) {
            const int off = (T * 16 + cc) * 64 + m * 16 + q * 4;
            const float4 w2 = *(const float4*)(W2 + off);
            const float4 w3 = *(const float4*)(W3 + off);
            U4 h, l;
            h.u[0] = pkrtz(w2.x, w2.y); h.u[1] = pkrtz(w2.z, w2.w);
            l.u[0] = pkrtz(lo0(h.u[0], w2.x), lo1(h.u[0], w2.y));
            l.u[1] = pkrtz(lo0(h.u[1], w2.z), lo1(h.u[1], w2.w));
            W2h[T][m] = h.v; W2l[T][m] = l.v;
            h.u[0] = pkrtz(w3.x, w3.y); h.u[1] = pkrtz(w3.z, w3.w);
            l.u[0] = pkrtz(lo0(h.u[0], w3.x), lo1(h.u[0], w3.y));
            l.u[1] = pkrtz(lo0(h.u[1], w3.z), lo1(h.u[1], w3.w));
            W3h[T][m] = h.v; W3l[T][m] = l.v;
        }

    float b2m[16], b3m[16], w4r[16];
    #pragma unroll
    for (int T = 0; T < 4; ++T)
        #pragma unroll
        for (int r = 0; r < 4; ++r) {
            const int row = T * 16 + q * 4 + r;
            b2m[T * 4 + r] = fwd ? b2[row] : 0.f;
            b3m[T * 4 + r] = fwd ? b3[row] : 0.f;
            w4r[T * 4 + r] = W4[row];
        }

    float A1v[16], w11v[16];
    {
        const float xs  = x[sbase + s];
        const float c0s = c0g[sbase + s];
        #pragma unroll
        for (int m = 0; m < 4; ++m)
            #pragma unroll
            for (int j = 0; j < 4; ++j) {
                const int k = m * 16 + q * 4 + j;
                w11v[m * 4 + j] = W1[k * 3 + 1];
                A1v[m * 4 + j]  = fmaf(xs, W1[k * 3 + 0],
                                       fmaf(c0s, W1[k * 3 + 2], b1[k]));
            }
    }

    float y = 0.0f;

    #pragma unroll 1
    for (int step = 0; step < 50; ++step) {
        // ---- layer 1 (fp32, registers) -> split B1 chunks ----
        U4 B1h[4], B1l[4];
        #pragma unroll
        for (int m = 0; m < 4; ++m) {
            float v[4];
            #pragma unroll
            for (int j = 0; j < 4; ++j) {
                const float w = w11v[m * 4 + j];
                const float z = fmaf(y, w, A1v[m * 4 + j]);
                v[j] = fwd ? fmaxf(z, 0.f) : (z > 0.f ? w : 0.f);
            }
            const unsigned h0 = pkrtz(v[0], v[1]);
            const unsigned h1 = pkrtz(v[2], v[3]);
            B1h[m].u[0] = h0; B1h[m].u[1] = h1;
            B1l[m].u[0] = pkrtz(lo0(h0, v[0]), lo1(h0, v[1]));
            B1l[m].u[1] = pkrtz(lo0(h1, v[2]), lo1(h1, v[3]));
        }
        // ---- layer 2: split MFMA, m-outer interleave (12-apart dep reuse) ----
        f32x4 aH[4], aLa[4], aLb[4];
        #pragma unroll
        for (int T = 0; T < 4; ++T) {
            aH[T][0] = b2m[T * 4 + 0]; aH[T][1] = b2m[T * 4 + 1];
            aH[T][2] = b2m[T * 4 + 2]; aH[T][3] = b2m[T * 4 + 3];
            aLa[T] = (f32x4){0.f, 0.f, 0.f, 0.f};
            aLb[T] = (f32x4){0.f, 0.f, 0.f, 0.f};
        }
        #pragma unroll
        for (int m = 0; m < 4; ++m) {
            #pragma unroll
            for (int T = 0; T < 4; ++T)
                aH[T]  = __builtin_amdgcn_mfma_f32_16x16x16f16(W2h[T][m], B1h[m].v, aH[T], 0, 0, 0);
            #pragma unroll
            for (int T = 0; T < 4; ++T)
                aLa[T] = __builtin_amdgcn_mfma_f32_16x16x16f16(W2h[T][m], B1l[m].v, aLa[T], 0, 0, 0);
            #pragma unroll
            for (int T = 0; T < 4; ++T)
                aLb[T] = __builtin_amdgcn_mfma_f32_16x16x16f16(W2l[T][m], B1h[m].v, aLb[T], 0, 0, 0);
        }
        // ---- combine; batch mask shfls; select + split -> B2 chunks ----
        float z2[16], rc2[16];
        #pragma unroll
        for (int k = 0; k < 16; ++k)
            z2[k] = fmaf(aLa[k >> 2][k & 3] + aLb[k >> 2][k & 3], LOINV, aH[k >> 2][k & 3]);
        #pragma unroll
        for (int k = 0; k < 16; ++k)
            rc2[k] = __shfl_xor(z2[k], 8);
        U4 B2h[4], B2l[4];
        #pragma unroll
        for (int T = 0; T < 4; ++T) {
            float v[4];
            #pragma unroll
            for (int r = 0; r < 4; ++r) {
                const float z = z2[T * 4 + r];
                v[r] = fwd ? fmaxf(z, 0.f) : (rc2[T * 4 + r] > 0.f ? z : 0.f);
            }
            const unsigned h0 = pkrtz(v[0], v[1]);
            const unsigned h1 = pkrtz(v[2], v[3]);
            B2h[T].u[0] = h0; B2h[T].u[1] = h1;
            B2l[T].u[0] = pkrtz(lo0(h0, v[0]), lo1(h0, v[1]));
            B2l[T].u[1] = pkrtz(lo0(h1, v[2]), lo1(h1, v[3]));
        }
        // ---- layer 3: split MFMA, same interleave ----
        #pragma unroll
        for (int T = 0; T < 4; ++T) {
            aH[T][0] = b3m[T * 4 + 0]; aH[T][1] = b3m[T * 4 + 1];
            aH[T][2] = b3m[T * 4 + 2]; aH[T][3] = b3m[T * 4 + 3];
            aLa[T] = (f32x4){0.f, 0.f, 0.f, 0.f};
            aLb[T] = (f32x4){0.f, 0.f, 0.f, 0.f};
        }
        #pragma unroll
        for (int m = 0; m < 4; ++m) {
            #pragma unroll
            for (int T = 0; T < 4; ++T)
                aH[T]  = __builtin_amdgcn_mfma_f32_16x16x16f16(W3h[T][m], B2h[m].v, aH[T], 0, 0, 0);
            #pragma unroll
            for (int T = 0; T < 4; ++T)
                aLa[T] = __builtin_amdgcn_mfma_f32_16x16x16f16(W3h[T][m], B2l[m].v, aLa[T], 0, 0, 0);
            #pragma unroll
            for (int T = 0; T < 4; ++T)
                aLb[T] = __builtin_amdgcn_mfma_f32_16x16x16f16(W3l[T][m], B2h[m].v, aLb[T], 0, 0, 0);
        }
        // ---- layer 4 (fp32): batch shfls; 4 parallel FMA chains; tree add ----
        float z3[16], rc3[16];
        #pragma unroll
        for (int k = 0; k < 16; ++k)
            z3[k] = fmaf(aLa[k >> 2][k & 3] + aLb[k >> 2][k & 3], LOINV, aH[k >> 2][k & 3]);
        #pragma unroll
        for (int k = 0; k < 16; ++k)
            rc3[k] = __shfl_xor(z3[k], 8);
        float gp[4] = {0.f, 0.f, 0.f, 0.f};
        #pragma unroll
        for (int T = 0; T < 4; ++T)
            #pragma unroll
            for (int r = 0; r < 4; ++r) {
                const int k = T * 4 + r;
                const float maskv = fwd ? z3[k] : rc3[k];   // z3 fwd (with bias)
                const float valv  = fwd ? rc3[k] : z3[k];   // dz3
                gp[T] = fmaf(w4r[k], (maskv > 0.f) ? valv : 0.f, gp[T]);
            }
        const float g = (gp[0] + gp[1]) + (gp[2] + gp[3]);
        // 3 parallel shfls (single latency window); commutative adds keep the
        // total bitwise-identical at every lane in the orbit -> uniform y.
        const float r1 = __shfl_xor(g, 16);
        const float r2 = __shfl_xor(g, 32);
        const float r3 = __shfl_xor(g, 48);
        y -= 0.1f * ((g + r1) + (r2 + r3));
    }
    if (lane < 8) out[sbase + lane] = y;
}

extern "C" void kernel_launch(void* const* d_in, const int* in_sizes, int n_in,
                              void* d_out, int out_size, void* d_ws, size_t ws_size,
                              hipStream_t stream) {
    const float* x  = (const float*)d_in[0];
    const float* c  = (const float*)d_in[1];
    const float* W1 = (const float*)d_in[2];
    const float* b1 = (const float*)d_in[3];
    const float* W2 = (const float*)d_in[4];
    const float* b2 = (const float*)d_in[5];
    const float* W3 = (const float*)d_in[6];
    const float* b3 = (const float*)d_in[7];
    const float* W4 = (const float*)d_in[8];
    // d_in[9] = b4: unused (only grad wrt y is needed, b4 drops out)
    float* c0  = (float*)d_ws;
    float* out = (float*)d_out;

    nn_kernel<<<BATCH / 8, 256, 0, stream>>>(c, c0);
    solve_kernel<<<BATCH / 8, 64, 0, stream>>>(x, c0, W1, b1, W2, b2, W3, b3, W4, out);
}

// Round 10
// 175.043 us; speedup vs baseline: 1.0537x; 1.0537x over previous
//
#include <hip/hip_runtime.h>

#define BATCH 8192
#define LOSC  2048.0f
#define LOINV (1.0f / 2048.0f)

typedef _Float16 f16x4 __attribute__((ext_vector_type(4)));
typedef __fp16   fp16x2 __attribute__((ext_vector_type(2)));
typedef float    f32x4 __attribute__((ext_vector_type(4)));

union PK2 { fp16x2 h; unsigned u; };
union U4  { f16x4 v; unsigned u[2]; };

__device__ __forceinline__ unsigned pkrtz(float a, float b) {
    PK2 p; p.h = __builtin_amdgcn_cvt_pkrtz(a, b); return p.u;
}
__device__ __forceinline__ float lo0(unsigned hp, float v) {
    PK2 p; p.u = hp; return (v - (float)p.h[0]) * LOSC;
}
__device__ __forceinline__ float lo1(unsigned hp, float v) {
    PK2 p; p.u = hp; return (v - (float)p.h[1]) * LOSC;
}

// ---------------------------------------------------------------------------
// Kernel 1: exact NN (CD=1). Reference distance sqrt(fl(dx*dx)) == |dx| in
// correctly-rounded fp32 -> compare fabsf(dx); first-index argmin preserved
// (strict < over ascending j), self excluded. ~5 us standalone.
// ---------------------------------------------------------------------------
__global__ __launch_bounds__(256) void nn_kernel(const float* __restrict__ c,
                                                 float* __restrict__ c0) {
    __shared__ float cs[BATCH];
    const int t = threadIdx.x;
    {
        const float4* cg = (const float4*)c;
        float4* cl = (float4*)cs;
        for (int j = t; j < BATCH / 4; j += 256) cl[j] = cg[j];
    }
    __syncthreads();
    const int part = t & 31;
    const int i    = blockIdx.x * 8 + (t >> 5);
    const float ci = cs[i];
    const int sj0 = ((i & 3) == 0) ? (i >> 2) : -1;
    const int sj1 = ((i & 3) == 1) ? (i >> 2) : -1;
    const int sj2 = ((i & 3) == 2) ? (i >> 2) : -1;
    const int sj3 = ((i & 3) == 3) ? (i >> 2) : -1;
    const float4* cs4 = (const float4*)cs;
    float bd0 = 3e38f, bd1 = 3e38f, bd2 = 3e38f, bd3 = 3e38f;
    int   bj0 = 0,     bj1 = 0,     bj2 = 0,     bj3 = 0;
    #pragma unroll 4
    for (int tt = 0; tt < 64; ++tt) {
        const int jj = part + (tt << 5);
        const float4 v = cs4[jj];
        float d0 = fabsf(ci - v.x);
        float d1 = fabsf(ci - v.y);
        float d2 = fabsf(ci - v.z);
        float d3 = fabsf(ci - v.w);
        if (jj == sj0) d0 = 3e38f;
        if (jj == sj1) d1 = 3e38f;
        if (jj == sj2) d2 = 3e38f;
        if (jj == sj3) d3 = 3e38f;
        if (d0 < bd0) { bd0 = d0; bj0 = jj; }
        if (d1 < bd1) { bd1 = d1; bj1 = jj; }
        if (d2 < bd2) { bd2 = d2; bj2 = jj; }
        if (d3 < bd3) { bd3 = d3; bj3 = jj; }
    }
    float best = bd0; int bestj = bj0 * 4 + 0;
    { const int j1 = bj1 * 4 + 1; if (bd1 < best || (bd1 == best && j1 < bestj)) { best = bd1; bestj = j1; } }
    { const int j2 = bj2 * 4 + 2; if (bd2 < best || (bd2 == best && j2 < bestj)) { best = bd2; bestj = j2; } }
    { const int j3 = bj3 * 4 + 3; if (bd3 < best || (bd3 == best && j3 < bestj)) { best = bd3; bestj = j3; } }
    #pragma unroll
    for (int off = 1; off < 32; off <<= 1) {
        const float od = __shfl_xor(best, off);
        const int   oj = __shfl_xor(bestj, off);
        if (od < best || (od == best && oj < bestj)) { best = od; bestj = oj; }
    }
    if (part == 0) c0[i] = cs[bestj];
}

// ---------------------------------------------------------------------------
// Kernel 2 (v10 = v7 + two surgical changes): 8 samples/wave, 1024 x 1 wave.
// Split-f16 via mfma_f32_16x16x16_f16 (K=16): B k-map (q*4+j) == C/D row map
// (q*4+r) -> zero-shfl inter-layer transform. All weights in registers.
// CHANGE 1 vs v7: per-T, aL split into aLa/aLb (dep distance 1 -> 3 in the
//   MFMA chains; transient regs only; combined right after the m-loop).
// CHANGE 2 vs v7: final reduce = 3 parallel shfl_xor(16/32/48) + commutative
//   sum (one DS latency window; y stays bitwise-uniform per lane orbit).
// Everything else bit-identical to the 110 us v7 kernel.
// ---------------------------------------------------------------------------
__global__ __launch_bounds__(64, 1) void solve_kernel(
    const float* __restrict__ x, const float* __restrict__ c0g,
    const float* __restrict__ W1, const float* __restrict__ b1,
    const float* __restrict__ W2, const float* __restrict__ b2,
    const float* __restrict__ W3, const float* __restrict__ b3,
    const float* __restrict__ W4, float* __restrict__ out)
{
    const int lane = threadIdx.x & 63;
    const int q  = lane >> 4;
    const int cc = lane & 15;
    const bool fwd = (cc < 8);
    const int s = cc & 7;
    const int sbase = blockIdx.x * 8;

    // ---- W2/W3 hi+lo fragments, all in registers ----
    // A-frag (T,m): lane holds W[(T*16+cc)][m*16 + q*4 + j], j=0..3 (float4)
    f16x4 W2h[4][4], W2l[4][4], W3h[4][4], W3l[4][4];
    #pragma unroll
    for (int T = 0; T < 4; ++T)
        #pragma unroll
        for (int m = 0; m < 4; ++m) {
            const int off = (T * 16 + cc) * 64 + m * 16 + q * 4;
            const float4 w2 = *(const float4*)(W2 + off);
            const float4 w3 = *(const float4*)(W3 + off);
            U4 h, l;
            h.u[0] = pkrtz(w2.x, w2.y); h.u[1] = pkrtz(w2.z, w2.w);
            l.u[0] = pkrtz(lo0(h.u[0], w2.x), lo1(h.u[0], w2.y));
            l.u[1] = pkrtz(lo0(h.u[1], w2.z), lo1(h.u[1], w2.w));
            W2h[T][m] = h.v; W2l[T][m] = l.v;
            h.u[0] = pkrtz(w3.x, w3.y); h.u[1] = pkrtz(w3.z, w3.w);
            l.u[0] = pkrtz(lo0(h.u[0], w3.x), lo1(h.u[0], w3.y));
            l.u[1] = pkrtz(lo0(h.u[1], w3.z), lo1(h.u[1], w3.w));
            W3h[T][m] = h.v; W3l[T][m] = l.v;
        }

    // ---- pre-masked biases + W4, C-layout rows T*16 + q*4 + r ----
    float b2m[16], b3m[16], w4r[16];
    #pragma unroll
    for (int T = 0; T < 4; ++T)
        #pragma unroll
        for (int r = 0; r < 4; ++r) {
            const int row = T * 16 + q * 4 + r;
            b2m[T * 4 + r] = fwd ? b2[row] : 0.f;
            b3m[T * 4 + r] = fwd ? b3[row] : 0.f;
            w4r[T * 4 + r] = W4[row];
        }

    // ---- layer-1 constants: B rows k = m*16 + q*4 + j ----
    float A1v[16], w11v[16];
    {
        const float xs  = x[sbase + s];
        const float c0s = c0g[sbase + s];
        #pragma unroll
        for (int m = 0; m < 4; ++m)
            #pragma unroll
            for (int j = 0; j < 4; ++j) {
                const int k = m * 16 + q * 4 + j;
                w11v[m * 4 + j] = W1[k * 3 + 1];
                A1v[m * 4 + j]  = fmaf(xs, W1[k * 3 + 0],
                                       fmaf(c0s, W1[k * 3 + 2], b1[k]));
            }
    }

    float y = 0.0f;

    #pragma unroll 1
    for (int step = 0; step < 50; ++step) {
        // ---- layer 1 (fp32, registers) -> split B1 chunks ----
        U4 B1h[4], B1l[4];
        #pragma unroll
        for (int m = 0; m < 4; ++m) {
            float v[4];
            #pragma unroll
            for (int j = 0; j < 4; ++j) {
                const float w = w11v[m * 4 + j];
                const float z = fmaf(y, w, A1v[m * 4 + j]);
                v[j] = fwd ? fmaxf(z, 0.f) : (z > 0.f ? w : 0.f);
            }
            const unsigned h0 = pkrtz(v[0], v[1]);
            const unsigned h1 = pkrtz(v[2], v[3]);
            B1h[m].u[0] = h0; B1h[m].u[1] = h1;
            B1l[m].u[0] = pkrtz(lo0(h0, v[0]), lo1(h0, v[1]));
            B1l[m].u[1] = pkrtz(lo0(h1, v[2]), lo1(h1, v[3]));
        }
        // ---- layer 2: split MFMA (K=16 x 4 chunks), 3 chains per tile ----
        f32x4 ZH[4], ZL[4];
        #pragma unroll
        for (int T = 0; T < 4; ++T) {
            f32x4 aH;
            aH[0] = b2m[T * 4 + 0]; aH[1] = b2m[T * 4 + 1];
            aH[2] = b2m[T * 4 + 2]; aH[3] = b2m[T * 4 + 3];
            f32x4 aLa = {0.f, 0.f, 0.f, 0.f};
            f32x4 aLb = {0.f, 0.f, 0.f, 0.f};
            #pragma unroll
            for (int m = 0; m < 4; ++m) {
                aH  = __builtin_amdgcn_mfma_f32_16x16x16f16(W2h[T][m], B1h[m].v, aH, 0, 0, 0);
                aLa = __builtin_amdgcn_mfma_f32_16x16x16f16(W2h[T][m], B1l[m].v, aLa, 0, 0, 0);
                aLb = __builtin_amdgcn_mfma_f32_16x16x16f16(W2l[T][m], B1h[m].v, aLb, 0, 0, 0);
            }
            ZH[T] = aH; ZL[T] = aLa + aLb;
        }
        // ---- combine + mask -> B2 chunks DIRECTLY (C-tile T == B-chunk T) ----
        U4 B2h[4], B2l[4];
        #pragma unroll
        for (int T = 0; T < 4; ++T) {
            float v[4];
            #pragma unroll
            for (int r = 0; r < 4; ++r) {
                const float z = fmaf(ZL[T][r], LOINV, ZH[T][r]);
                const float recv = __shfl_xor(z, 8);
                v[r] = fwd ? fmaxf(z, 0.f) : (recv > 0.f ? z : 0.f);
            }
            const unsigned h0 = pkrtz(v[0], v[1]);
            const unsigned h1 = pkrtz(v[2], v[3]);
            B2h[T].u[0] = h0; B2h[T].u[1] = h1;
            B2l[T].u[0] = pkrtz(lo0(h0, v[0]), lo1(h0, v[1]));
            B2l[T].u[1] = pkrtz(lo0(h1, v[2]), lo1(h1, v[3]));
        }
        // ---- layer 3: split MFMA, 3 chains per tile ----
        #pragma unroll
        for (int T = 0; T < 4; ++T) {
            f32x4 aH;
            aH[0] = b3m[T * 4 + 0]; aH[1] = b3m[T * 4 + 1];
            aH[2] = b3m[T * 4 + 2]; aH[3] = b3m[T * 4 + 3];
            f32x4 aLa = {0.f, 0.f, 0.f, 0.f};
            f32x4 aLb = {0.f, 0.f, 0.f, 0.f};
            #pragma unroll
            for (int m = 0; m < 4; ++m) {
                aH  = __builtin_amdgcn_mfma_f32_16x16x16f16(W3h[T][m], B2h[m].v, aH, 0, 0, 0);
                aLa = __builtin_amdgcn_mfma_f32_16x16x16f16(W3h[T][m], B2l[m].v, aLa, 0, 0, 0);
                aLb = __builtin_amdgcn_mfma_f32_16x16x16f16(W3l[T][m], B2h[m].v, aLb, 0, 0, 0);
            }
            ZH[T] = aH; ZL[T] = aLa + aLb;
        }
        // ---- layer 4 (fp32): g = W4 . (1[z3>0] * dz3) ----
        float g = 0.f;
        #pragma unroll
        for (int T = 0; T < 4; ++T)
            #pragma unroll
            for (int r = 0; r < 4; ++r) {
                const float z = fmaf(ZL[T][r], LOINV, ZH[T][r]);
                const float recv  = __shfl_xor(z, 8);
                const float maskv = fwd ? z : recv;   // z3 fwd (with bias)
                const float valv  = fwd ? recv : z;   // dz3
                g = fmaf(w4r[T * 4 + r], (maskv > 0.f) ? valv : 0.f, g);
            }
        // 3 parallel shfls (single latency window); commutative adds keep the
        // total bitwise-identical at every lane in the orbit -> uniform y.
        const float r1 = __shfl_xor(g, 16);
        const float r2 = __shfl_xor(g, 32);
        const float r3 = __shfl_xor(g, 48);
        y -= 0.1f * ((g + r1) + (r2 + r3));
    }
    if (lane < 8) out[sbase + lane] = y;
}

extern "C" void kernel_launch(void* const* d_in, const int* in_sizes, int n_in,
                              void* d_out, int out_size, void* d_ws, size_t ws_size,
                              hipStream_t stream) {
    const float* x  = (const float*)d_in[0];
    const float* c  = (const float*)d_in[1];
    const float* W1 = (const float*)d_in[2];
    const float* b1 = (const float*)d_in[3];
    const float* W2 = (const float*)d_in[4];
    const float* b2 = (const float*)d_in[5];
    const float* W3 = (const float*)d_in[6];
    const float* b3 = (const float*)d_in[7];
    const float* W4 = (const float*)d_in[8];
    // d_in[9] = b4: unused (only grad wrt y is needed, b4 drops out)
    float* c0  = (float*)d_ws;
    float* out = (float*)d_out;

    nn_kernel<<<BATCH / 8, 256, 0, stream>>>(c, c0);
    solve_kernel<<<BATCH / 8, 64, 0, stream>>>(x, c0, W1, b1, W2, b2, W3, b3, W4, out);
}